// Round 6
// baseline (54.070 us; speedup 1.0000x reference)
//
#include <hip/hip_runtime.h>

// LinearConv2D fused v6: bf16 MFMA + ring-buffered global_load_lds with
// counted vmcnt across raw s_barriers (T3/T4 pattern; no vmcnt(0) drain).
// x[8,128,32,1024] f32, weight[128,16,32,16] f32 -> out[8,128,17,257] f32
// y[n,t] = sum_{f in {2fo-1,2fo}} sum_{d,w} x[b,g16+d,f,4t+w-8]*wt[g16+n,d,f,w]
// Slice = (f, d-pair); 16 (or 8) slices; ring of 4 LDS slots, staged 3 ahead.
// Body: waitcnt vmcnt(4) [own slice-q loads done] -> s_barrier -> 8 ds_read
// + cvt + 4 MFMA -> issue stage(q+3). Tail steps wait vmcnt(2)/vmcnt(0).
// Datapath (fragment maps + LDS layout) identical to v5 (verified pass).

typedef __attribute__((ext_vector_type(8))) short short8v;
typedef __attribute__((ext_vector_type(4))) float f32x4;

#define TPB 256

static __device__ __forceinline__ short f2bf(float f) {   // RNE f32->bf16
    unsigned u = __builtin_bit_cast(unsigned, f);
    u += 0x7FFFu + ((u >> 16) & 1u);
    return (short)(u >> 16);
}

__global__ __launch_bounds__(TPB, 4) void lconv6(
    const float* __restrict__ x,   // [8,128,32,1024]
    const float* __restrict__ wt,  // [128,16,32,16]
    float* __restrict__ out)       // [8,128,17,257]
{
    __shared__ __attribute__((aligned(16))) float xl[8320]; // 4 slots x 2 x 1040
    __shared__ float red[4][16];

    const int fo = blockIdx.x, g = blockIdx.y, b = blockIdx.z;
    const int tid  = threadIdx.x;
    const int lane = tid & 63;
    const int wid  = __builtin_amdgcn_readfirstlane(tid >> 6);
    const int cc = lane & 15;          // fragment column (t or n)
    const int kq = lane >> 4;          // k-group 0..3

    int fvals[2]; int nf = 0;
    if (2*fo - 1 >= 0) fvals[nf++] = 2*fo - 1;
    if (2*fo < 32)     fvals[nf++] = 2*fo;
    const int f0 = fvals[0];
    const int f1 = (nf > 1) ? fvals[1] : f0;

    const int BG = b*128 + g*16;
    const int wlc = (g*16 + cc)*8192 + (kq>>1)*512 + 8*(kq&1);
    const int rbase = (kq>>1)*1040 + 4*cc + 8*(kq&1) + 256*wid;

    // stage one (f, d-pair) slice into ring slot: 2 rows, 4KB each via LDS-DMA
    auto stage2 = [&](int f_, int dp_, int slot_) {
        #pragma unroll
        for (int r = 0; r < 2; ++r) {
            const float* src = x + ((size_t)((BG + 2*dp_ + r)*32 + f_))*1024 + tid*4;
            __builtin_amdgcn_global_load_lds(
                (const __attribute__((address_space(1))) void*)src,
                (__attribute__((address_space(3))) void*)&xl[slot_*2080 + r*1040 + 8 + tid*4],
                16, 0, 0);
        }
    };

    // zero pads for all 4 slots x 2 rows (interior [8,1032) is DMA-covered)
    if (tid < 128) {
        const int row = tid >> 4, p = tid & 15;
        xl[row*1040 + (p < 8 ? p : 1024 + p)] = 0.f;
    }

    // prologue: stage slices 0,1,2 (all f0)
    stage2(f0, 0, 0);
    stage2(f0, 1, 1);
    stage2(f0, 2, 2);

    f32x4 acc[4];
    #pragma unroll
    for (int t = 0; t < 4; ++t) acc[t] = (f32x4){0.f, 0.f, 0.f, 0.f};

    __syncthreads();   // drains prologue; publishes pads; resets vmcnt model

    short8v afr[8];

    for (int s = 0; s < nf; ++s) {
        const int f = (s == 0) ? f0 : f1;

        // (re)load A-frags for this f: 8 d-pairs, 32B/lane each (L1/L2-hot)
        #pragma unroll
        for (int dp = 0; dp < 8; ++dp) {
            const float* wp = wt + wlc + dp*1024 + f*16;
            const float4 w0 = *(const float4*)wp;
            const float4 w1 = *(const float4*)(wp + 4);
            union { short8v s8; short h[8]; } u;
            u.h[0]=f2bf(w0.x); u.h[1]=f2bf(w0.y); u.h[2]=f2bf(w0.z); u.h[3]=f2bf(w0.w);
            u.h[4]=f2bf(w1.x); u.h[5]=f2bf(w1.y); u.h[6]=f2bf(w1.z); u.h[7]=f2bf(w1.w);
            afr[dp] = u.s8;
        }

        const bool tail = (s == nf - 1);
        #pragma unroll
        for (int dp = 0; dp < 8; ++dp) {
            // counted wait: retire own loads for slice q = s*8+dp;
            // keep later slices' loads in flight across the barrier
            if (tail && dp == 6)      asm volatile("s_waitcnt vmcnt(2)" ::: "memory");
            else if (tail && dp == 7) asm volatile("s_waitcnt vmcnt(0)" ::: "memory");
            else                      asm volatile("s_waitcnt vmcnt(4)" ::: "memory");
            __builtin_amdgcn_sched_barrier(0);
            __builtin_amdgcn_s_barrier();

            // compute slice q from ring slot dp&3
            const float* xp = xl + (dp & 3)*2080 + rbase;
            #pragma unroll
            for (int tt = 0; tt < 4; ++tt) {
                const float4 a0 = *(const float4*)(xp + 64*tt);
                const float4 a1 = *(const float4*)(xp + 64*tt + 4);
                union { short8v s8; short h[8]; } ub;
                ub.h[0]=f2bf(a0.x); ub.h[1]=f2bf(a0.y); ub.h[2]=f2bf(a0.z); ub.h[3]=f2bf(a0.w);
                ub.h[4]=f2bf(a1.x); ub.h[5]=f2bf(a1.y); ub.h[6]=f2bf(a1.z); ub.h[7]=f2bf(a1.w);
                acc[tt] = __builtin_amdgcn_mfma_f32_16x16x32_bf16(
                              afr[dp], ub.s8, acc[tt], 0, 0, 0);
            }

            // stage slice q+3 into slot (q+3)%4 (== slot read at q-1: WAR-safe,
            // every wave passed this body's barrier after finishing q-1)
            const int q3 = s*8 + dp + 3;
            if (q3 < nf*8) {
                const int f3 = ((q3 >> 3) == 0) ? f0 : f1;
                stage2(f3, (dp + 3) & 7, (dp + 3) & 3);
            }
        }
    }

    __syncthreads();   // everything retired; reuse xl for epilogue

    // ---- epilogue: per-wave transpose tile [16n][68] -> coalesced stores ----
    {
        float* tp = xl + wid*1088;
        #pragma unroll
        for (int tt = 0; tt < 4; ++tt)
            #pragma unroll
            for (int r = 0; r < 4; ++r) {
                float v = acc[tt][r];
                v = (v > 0.f) ? v : 0.01f*v;
                tp[(kq*4 + r)*68 + tt*16 + cc] = v;
            }
        #pragma unroll
        for (int p = 0; p < 4; ++p) {
            const int linear = p*64 + lane;
            const int nn = linear >> 4;
            const int c4 = linear & 15;
            const float4 vv = *(const float4*)(tp + nn*68 + c4*4);
            const size_t ob = (size_t)(BG + nn)*4369 + (size_t)fo*257
                            + wid*64 + c4*4;
            out[ob + 0] = vv.x; out[ob + 1] = vv.y;
            out[ob + 2] = vv.z; out[ob + 3] = vv.w;
        }
    }

    // ---- t = 256 edge column, fp32 (window taps w=0..7 only) ----
    {
        const int n = tid & 15;
        const int d = tid >> 4;
        const size_t xrow_bg = (size_t)BG * 32768;
        float p = 0.f;
        for (int s = 0; s < nf; ++s) {
            const int f = (s == 0) ? f0 : f1;
            const float* xr = x + xrow_bg + (size_t)d*32768 + (size_t)f*1024 + 1016;
            const float* wr = wt + (size_t)(g*16 + n)*8192 + (size_t)d*512 + f*16;
            #pragma unroll
            for (int w = 0; w < 8; ++w) p = fmaf(xr[w], wr[w], p);
        }
        p += __shfl_xor(p, 16);
        p += __shfl_xor(p, 32);
        if (lane < 16) red[wid][lane] = p;
        __syncthreads();
        if (tid < 16) {
            float v = red[0][tid] + red[1][tid] + red[2][tid] + red[3][tid];
            v = (v > 0.f) ? v : 0.01f*v;
            out[(size_t)(BG + tid)*4369 + (size_t)fo*257 + 256] = v;
        }
    }
}

extern "C" void kernel_launch(void* const* d_in, const int* in_sizes, int n_in,
                              void* d_out, int out_size, void* d_ws, size_t ws_size,
                              hipStream_t stream) {
    const float* x  = (const float*)d_in[0];
    const float* wt = (const float*)d_in[1];
    float* out      = (float*)d_out;
    dim3 grid(17, 8, 8);   // (fo, g, b)
    lconv6<<<grid, TPB, 0, stream>>>(x, wt, out);
}